// Round 10
// baseline (392.083 us; speedup 1.0000x reference)
//
#include <hip/hip_runtime.h>

// WaveFDTD2D, persistent kernel, ELASTIC per-wave flag sync (r22).
// r16-r21 evidence: round wall ~8us invariant to barrier COUNT, protocol
// trims, per-wave ILP; VALU issue only ~57us of 260. The stall is the
// 16-wave lockstep: every substep all waves reconverge on __syncthreads then
// hit the same ds_read latency with zero slack. r22 removes the per-substep
// barrier: wave w only consumes rows of waves w+-1, so it polls LDS flags
// wflag[w+-1] (absolute substep count; release store emits the lgkmcnt drain
// of the row ds_writes, acquire poll orders the halo reads). RAW and WAR
// both need neighbors >= base+s before substep s (double buffer): drift
// bound 1 between adjacent waves -> elastic chain instead of rigid convoy.
// Substep 0 needs no poll (global x-halo, r20b scheme; cross-round WAR
// covered by the single per-round pre-publish __syncthreads).
// Receivers: register-captured by the OWNING thread (post-injection rCur[i])
// and stored straight to global each substep -> no LDS receiver read, no
// cross-wave coupling, rv[16] registers freed.
// Everything else verbatim from r20b (passed, 262us): agent-scope coherent-
// point field exchange, fenceless 8-neighbor global counter sync, all-wave
// polling, exact L1 cone skip, no prefill, guard rows, V2-in-registers.

#define NXd 512
#define NZd 512
#define NSTEPSd 512
#define NRECd 128
#define DT2f 1.0e-6f
#define INVf 1.0e-2f
#define TBk 16
#define TIk 32
#define EXTk 64
#define NTILEk 16
#define PADk 16
#define PWk 544              // NXd + 2*PADk = 16*34
#define LROWS 66             // 1 dummy + 64 ext rows + 1 dummy
#define NROUNDS (NSTEPSd / TBk)
#define MAXR 8               // max receivers owned by one thread

__device__ __forceinline__ float dpp_shr1(float x) {  // lane i <- lane i-1
    int v = __builtin_amdgcn_update_dpp(0, __builtin_bit_cast(int, x),
                                        0x138, 0xF, 0xF, false);  // WAVE_SHR:1
    return __builtin_bit_cast(float, v);
}
__device__ __forceinline__ float dpp_shl1(float x) {  // lane i <- lane i+1
    int v = __builtin_amdgcn_update_dpp(0, __builtin_bit_cast(int, x),
                                        0x130, 0xF, 0xF, false);  // WAVE_SHL:1
    return __builtin_bit_cast(float, v);
}

// Coherent-point (agent-scope) field accesses: bypass L1/L2, hit L3.
__device__ __forceinline__ float2 ldg_f2(const float2* p) {
    unsigned long long v = __hip_atomic_load(
        (const unsigned long long*)p, __ATOMIC_RELAXED, __HIP_MEMORY_SCOPE_AGENT);
    return __builtin_bit_cast(float2, v);
}
__device__ __forceinline__ float ldg_f1(const float* p) {
    unsigned v = __hip_atomic_load(
        (const unsigned*)p, __ATOMIC_RELAXED, __HIP_MEMORY_SCOPE_AGENT);
    return __builtin_bit_cast(float, v);
}
__device__ __forceinline__ void stg_f2(float2* p, float2 x) {
    __hip_atomic_store((unsigned long long*)p,
                       __builtin_bit_cast(unsigned long long, x),
                       __ATOMIC_RELAXED, __HIP_MEMORY_SCOPE_AGENT);
}

__global__ __launch_bounds__(1024) void fdtd_persist(
    const float* __restrict__ vel, const float* __restrict__ source,
    const int* __restrict__ src_x, const int* __restrict__ src_z,
    const int* __restrict__ rec_x, const int* __restrict__ rec_z,
    float2* __restrict__ PA, float2* __restrict__ PB,
    float* __restrict__ out, unsigned* __restrict__ done)
{
    __shared__ float sb[2][LROWS * EXTk];
    __shared__ int wflag[16 * 16];   // per-wave progress, 64B-strided slots

    const int tid = threadIdx.x;
    const int w   = tid >> 6;       // 16 waves, wave w owns ext rows 4w..4w+3
    const int ez  = tid & 63;       // lane -> ext z coord
    const int bx = blockIdx.x, by = blockIdx.y;
    const int gx0 = by * TIk;
    const int gz0 = bx * TIk;
    const int ox = gx0 - TBk, oz = gz0 - TBk;
    const int myid = (by * NTILEk + bx) * 32;   // 128B-strided counter slot

    // ---- Block-local init: zero own 34x34 padded patch of PA and PB ----
    for (int i = tid; i < 34 * 34; i += 1024) {
        const int p = (by * 34 + i / 34) * PWk + (bx * 34 + i % 34);
        stg_f2(&PA[p], make_float2(0.f, 0.f));
        stg_f2(&PB[p], make_float2(0.f, 0.f));
    }

    // ---- Receiver ownership by COMPUTING thread (register capture) ----
    // Thread (w, ez) owns cells (ext rows 4w..4w+3, col ez). Scan all 128
    // receivers; record (index, register slot) for those on my cells.
    int nR = 0; int rSlot[MAXR]; int rReg[MAXR];
    for (int r = 0; r < NRECd; ++r) {
        const int er = rec_x[r] - ox, ec = rec_z[r] - oz;
        if (er >= TBk && er < TBk + TIk && ec >= TBk && ec < TBk + TIk &&
            ec == ez && (er >> 2) == w && nR < MAXR) {
            rSlot[nR] = r; rReg[nR] = er & 3; ++nR;
        }
    }
    // Zero owned receivers' out rows (harness poisons; skipped rounds = 0).
    for (int j = 0; j < nR; ++j) {
        float4* o4 = (float4*)&out[rSlot[j] * NSTEPSd];
        for (int q = 0; q < NSTEPSd / 4; ++q) o4[q] = make_float4(0.f, 0.f, 0.f, 0.f);
    }

    // V2 in 4 registers per thread: v^2*dt^2/(dx*dz), 0 in the apron.
    float rV2i[4];
    {
        const int fz = oz + ez;
        #pragma unroll
        for (int i = 0; i < 4; ++i) {
            const int fx = ox + 4 * w + i;
            float v2 = 0.f;
            if (fx >= 0 && fx < NXd && fz >= 0 && fz < NZd) {
                float v = vel[fx * NZd + fz];
                v2 = v * v * (DT2f * INVf);
            }
            rV2i[i] = v2;
        }
    }

    // Dummy LDS rows (0 and 65) zero in BOTH buffers; never rewritten.
    if (w == 0) {
        sb[0][ez] = 0.f;
        sb[0][(LROWS - 1) * EXTk + ez] = 0.f;
        sb[1][ez] = 0.f;
        sb[1][(LROWS - 1) * EXTk + ez] = 0.f;
    }
    if (ez == 0) wflag[w * 16] = 0;   // own progress slot

    // Source ownership (owner = lane ezs of wave exs>>2, register exs&3).
    const int sx = *src_x, sz = *src_z;
    const int exs = sx - ox, ezs = sz - oz;
    const bool srcHere = (exs >= 0 && exs < EXTk && ezs >= 0 && ezs < EXTk) &&
                         (tid == (((exs >> 2) << 6) | ezs));

    // Exact L1 cone: active at round k iff dman <= 16k+17.
    const int dxm = max(0, max(ox - sx, sx - (ox + EXTk - 1)));
    const int dzm = max(0, max(oz - sz, sz - (oz + EXTk - 1)));
    const int dman = dxm + dzm;
    const int kAct = dman <= (TBk + 1) ? 0 : (dman - (TBk + 1) + TBk - 1) / TBk;

    // Global neighbor polling: lanes 0-7 of each wave watch the 8 neighbors.
    const int lane = tid & 63;
    int nb = myid;
    if (lane < 8) {
        const int d = (lane < 4) ? lane : lane + 1;       // skip center
        const int ny = min(NTILEk - 1, max(0, by + d / 3 - 1));
        const int nx = min(NTILEk - 1, max(0, bx + d % 3 - 1));
        nb = (ny * NTILEk + nx) * 32;
    }

    const int pbase = (gx0 + 4 * w) * PWk + gz0 + ez;  // padded global index
    const int fbase = 4 * w * EXTk + ez;   // buffer row 4w (ext row 4w-1)

    // Publish init + entire cone-skipped prefix in one release store
    // (barrier drains every wave's vmcnt; agent stores visible at L3).
    __syncthreads();
    if (tid == 0)
        __hip_atomic_store(&done[myid], (unsigned)(kAct + 1),
                           __ATOMIC_RELAXED, __HIP_MEMORY_SCOPE_AGENT);

    int base = 0;   // absolute substep counter base (block-uniform)

    // ---- Rounds kAct..31; monotone cone => always active once started ----
    for (int k = kAct; k < NROUNDS; ++k) {
        const int t0 = TBk * k;

        // Per-wave wait: 8 neighbor BLOCKS finished round k-1.
        if (lane < 8) {
            const unsigned tgt = (unsigned)(k + 1);
            for (;;) {
                unsigned seen = __hip_atomic_load(&done[nb], __ATOMIC_RELAXED,
                                                  __HIP_MEMORY_SCOPE_AGENT);
                if (seen >= tgt) break;
                if (seen + 1 < tgt) __builtin_amdgcn_s_sleep(16);
                else                __builtin_amdgcn_s_sleep(1);
            }
        }

        float2* __restrict__ Pin  = (k & 1) ? PB : PA;
        float2* __restrict__ Pout = (k & 1) ? PA : PB;

        // Unconditional padded agent loads (apron zeros / tolerated rim).
        float2 co[4];
        #pragma unroll
        for (int i = 0; i < 4; ++i) co[i] = ldg_f2(&Pin[pbase + i * PWk]);
        // Substep-0 x-halo direct from global (guard rows keep it in-bounds).
        const float huG = ldg_f1((const float*)&Pin[pbase - PWk]);
        const float hdG = ldg_f1((const float*)&Pin[pbase + 4 * PWk]);

        float rCur[4], rOld[4];
        #pragma unroll
        for (int i = 0; i < 4; ++i) { rCur[i] = co[i].x; rOld[i] = co[i].y; }

        float sv[TBk];
        if (srcHere) {
            #pragma unroll
            for (int s = 0; s < TBk; ++s) sv[s] = source[t0 + s] * DT2f;
        }

        // ---- 16 sub-steps, elastic flag-synced (NO block barrier) ----
        #pragma unroll
        for (int s = 0; s < TBk; ++s) {
            // Poll waves w-1, w+1: their substep s-1 reads AND writes done
            // (RAW: halo rows ready; WAR: they left the buffer I now write).
            // s=0 needs no poll: halo from global, cross-round WAR covered
            // by the per-round pre-publish __syncthreads.
            if (s > 0) {
                const int tgt = base + s;
                if (w > 0)
                    while (__hip_atomic_load(&wflag[(w - 1) * 16],
                                             __ATOMIC_ACQUIRE,
                                             __HIP_MEMORY_SCOPE_WORKGROUP) < tgt)
                        __builtin_amdgcn_s_sleep(1);
                if (w < 15)
                    while (__hip_atomic_load(&wflag[(w + 1) * 16],
                                             __ATOMIC_ACQUIRE,
                                             __HIP_MEMORY_SCOPE_WORKGROUP) < tgt)
                        __builtin_amdgcn_s_sleep(1);
            }
            const float* cur = sb[s & 1];
            float* nxt = sb[(s & 1) ^ 1];
            // x-halo: s=0 from global regs; s>=1 wave-uniform ds_read2st64
            // (ext rows 4w-1, 4w+4; edge waves hit zero dummies).
            const float up0 = (s == 0) ? huG : cur[fbase];
            const float dn3 = (s == 0) ? hdG : cur[fbase + 5 * EXTk];
            float nv[4];
            #pragma unroll
            for (int i = 0; i < 4; ++i) {
                const float up = (i == 0) ? up0 : rCur[i - 1];
                const float dn = (i == 3) ? dn3 : rCur[i + 1];
                const float lf = dpp_shr1(rCur[i]);     // z-1 neighbor
                const float rt = dpp_shl1(rCur[i]);     // z+1 neighbor
                const float sum = (up + dn) + (lf + rt);
                const float t4 = __builtin_fmaf(-4.0f, rCur[i], sum);
                const float pm = __builtin_fmaf(2.0f, rCur[i], -rOld[i]);
                nv[i] = __builtin_fmaf(rV2i[i], t4, pm);
            }
            #pragma unroll
            for (int i = 0; i < 4; ++i) {
                rOld[i] = rCur[i];
                rCur[i] = nv[i];
                nxt[fbase + (1 + i) * EXTk] = nv[i];    // buffer row 4w+1+i
            }
            // Source injection (post-stencil, pre-release, pre-recording).
            if (srcHere) {
                #pragma unroll
                for (int i = 0; i < 4; ++i) {
                    if (i == (exs & 3)) {
                        rCur[i] += sv[s];
                        nxt[(exs + 1) * EXTk + ezs] = rCur[i];
                    }
                }
            }
            // Release own progress: lgkmcnt drain of the row writes is
            // implied by the RELEASE store; lane 0 only (broadcast flag).
            if (ez == 0)
                __hip_atomic_store(&wflag[w * 16], base + s + 1,
                                   __ATOMIC_RELEASE, __HIP_MEMORY_SCOPE_WORKGROUP);
            // Receiver capture from registers (post-injection), straight to
            // global; fire-and-forget, drained by the round-end barrier.
            #pragma unroll
            for (int j = 0; j < MAXR; ++j) {
                if (j < nR) {
                    const int rr = rReg[j];
                    const float v = rr == 0 ? rCur[0] : rr == 1 ? rCur[1]
                                  : rr == 2 ? rCur[2] : rCur[3];
                    out[rSlot[j] * NSTEPSd + t0 + s] = v;
                }
            }
        }
        base += TBk;

        // Store interior (ext rows 16..47 = waves 4..11, ez 16..47): agent
        // stores, visible to neighbors' agent loads without any fence.
        if (w >= 4 && w < 12 && ez >= TBk && ez < EXTk - TBk) {
            #pragma unroll
            for (int i = 0; i < 4; ++i)
                stg_f2(&Pout[pbase + i * PWk], make_float2(rCur[i], rOld[i]));
        }

        // Single per-round barrier: drains every wave's vmcnt before the
        // publish, and serializes rounds block-internally (cross-round WAR).
        __syncthreads();
        if (tid == 0)
            __hip_atomic_store(&done[myid], (unsigned)(k + 2),
                               __ATOMIC_RELAXED, __HIP_MEMORY_SCOPE_AGENT);
    }
}

extern "C" void kernel_launch(void* const* d_in, const int* in_sizes, int n_in,
                              void* d_out, int out_size, void* d_ws, size_t ws_size,
                              hipStream_t stream) {
    const float* vel    = (const float*)d_in[0];
    const float* source = (const float*)d_in[1];
    const int*   src_x  = (const int*)d_in[2];
    const int*   src_z  = (const int*)d_in[3];
    const int*   rec_x  = (const int*)d_in[4];
    const int*   rec_z  = (const int*)d_in[5];
    float* out = (float*)d_out;

    const size_t FP = (size_t)PWk * PWk;
    // Guard rows: [guard PWk][PA FP][PB FP][guard PWk][DONE].
    float2* base = (float2*)d_ws;
    float2* PA = base + PWk;
    float2* PB = PA + FP;
    unsigned* DONE = (unsigned*)(PB + FP + PWk);   // 256 counters, 128B stride

    hipMemsetAsync(DONE, 0, (size_t)NTILEk * NTILEk * 32 * sizeof(unsigned), stream);

    void* args[] = {(void*)&vel, (void*)&source, (void*)&src_x, (void*)&src_z,
                    (void*)&rec_x, (void*)&rec_z, (void*)&PA, (void*)&PB,
                    (void*)&out, (void*)&DONE};
    hipLaunchCooperativeKernel((void*)fdtd_persist, dim3(NTILEk, NTILEk),
                               dim3(1024), args, 0, stream);
}

// Round 14
// 343.227 us; speedup vs baseline: 1.1423x; 1.1423x over previous
//
#include <hip/hip_runtime.h>

// WaveFDTD2D, persistent fenceless-sync kernel, split-dependency polling (r26).
// CASE CLOSED on 2 blocks/CU: cooperative launcher caps this kernel at
// 1 block/CU (512-block coop launches were REJECTED -> all-zero output ->
// absmax == max|ref| == 1.49e-6 bit-identical in r17/r23); 512-block REGULAR
// launch (r25) hung the container (resident blocks spin on never-dispatched
// neighbors). Family dead by evidence.
// r26 = r20b (validated 262us) + poll split by actual dependency:
//  - LOAD-SIDE SUBSET POLL at round start: wave w polls only neighbors its
//    round-k reads touch. w0-3:{NW,N,NE} w4:{NW,N,NE,W,E} w5-10:{W,E}
//    w11:{W,E,SW,S,SE} w12-15:{SW,S,SE}. A late S neighbor no longer stalls
//    the N-half waves; their loads + s=0 slide under the straggler.
//  - STORE-SIDE FULL POLL after the 16 substeps, before Pout stores (WAR
//    gate: Pout(k) == neighbors' Pin(k-1)). 16 substeps later it is nearly
//    always satisfied -> ~free.
// Everything else byte-identical to r20b: agent-scope coherent-point field
// exchange, all-wave-lane polling idiom, no prefill (s=0 x-halo from global,
// guard rows), exact L1 cone skip + one-shot prefix publish, dummy zero LDS
// rows, V2-in-registers, post-publish receiver flush.

#define NXd 512
#define NZd 512
#define NSTEPSd 512
#define NRECd 128
#define DT2f 1.0e-6f
#define INVf 1.0e-2f
#define TBk 16
#define TIk 32
#define EXTk 64
#define NTILEk 16
#define PADk 16
#define PWk 544              // NXd + 2*PADk = 16*34
#define LROWS 66             // 1 dummy + 64 ext rows + 1 dummy
#define NROUNDS (NSTEPSd / TBk)

__device__ __forceinline__ float dpp_shr1(float x) {  // lane i <- lane i-1
    int v = __builtin_amdgcn_update_dpp(0, __builtin_bit_cast(int, x),
                                        0x138, 0xF, 0xF, false);  // WAVE_SHR:1
    return __builtin_bit_cast(float, v);
}
__device__ __forceinline__ float dpp_shl1(float x) {  // lane i <- lane i+1
    int v = __builtin_amdgcn_update_dpp(0, __builtin_bit_cast(int, x),
                                        0x130, 0xF, 0xF, false);  // WAVE_SHL:1
    return __builtin_bit_cast(float, v);
}

// Coherent-point (agent-scope) field accesses: bypass L1/L2, hit L3.
__device__ __forceinline__ float2 ldg_f2(const float2* p) {
    unsigned long long v = __hip_atomic_load(
        (const unsigned long long*)p, __ATOMIC_RELAXED, __HIP_MEMORY_SCOPE_AGENT);
    return __builtin_bit_cast(float2, v);
}
__device__ __forceinline__ float ldg_f1(const float* p) {
    unsigned v = __hip_atomic_load(
        (const unsigned*)p, __ATOMIC_RELAXED, __HIP_MEMORY_SCOPE_AGENT);
    return __builtin_bit_cast(float, v);
}
__device__ __forceinline__ void stg_f2(float2* p, float2 x) {
    __hip_atomic_store((unsigned long long*)p,
                       __builtin_bit_cast(unsigned long long, x),
                       __ATOMIC_RELAXED, __HIP_MEMORY_SCOPE_AGENT);
}

__device__ __forceinline__ void poll_ge(unsigned* p, unsigned tgt) {
    for (;;) {
        unsigned seen = __hip_atomic_load(p, __ATOMIC_RELAXED,
                                          __HIP_MEMORY_SCOPE_AGENT);
        if (seen >= tgt) break;
        if (seen + 1 < tgt) __builtin_amdgcn_s_sleep(16);
        else                __builtin_amdgcn_s_sleep(1);
    }
}

__global__ __launch_bounds__(1024) void fdtd_persist(
    const float* __restrict__ vel, const float* __restrict__ source,
    const int* __restrict__ src_x, const int* __restrict__ src_z,
    const int* __restrict__ rec_x, const int* __restrict__ rec_z,
    float2* __restrict__ PA, float2* __restrict__ PB,
    float* __restrict__ out, unsigned* __restrict__ done)
{
    __shared__ float sb[2][LROWS * EXTk];

    const int tid = threadIdx.x;
    const int w   = tid >> 6;       // 16 waves, wave w owns ext rows 4w..4w+3
    const int ez  = tid & 63;       // lane -> ext z coord
    const int bx = blockIdx.x, by = blockIdx.y;
    const int gx0 = by * TIk;
    const int gz0 = bx * TIk;
    const int ox = gx0 - TBk, oz = gz0 - TBk;
    const int myid = (by * NTILEk + bx) * 32;   // 128B-strided counter slot

    // ---- Block-local init: zero own 34x34 padded patch of PA and PB ----
    for (int i = tid; i < 34 * 34; i += 1024) {
        const int p = (by * 34 + i / 34) * PWk + (bx * 34 + i % 34);
        stg_f2(&PA[p], make_float2(0.f, 0.f));
        stg_f2(&PB[p], make_float2(0.f, 0.f));
    }

    // O(1) receiver ownership; owning block zeros its receivers' out rows.
    bool rOwn = false; int rIdx = 0;
    if (tid < NRECd) {
        const int rx = rec_x[tid], rz = rec_z[tid];
        rOwn = (rx >= gx0 && rx < gx0 + TIk && rz >= gz0 && rz < gz0 + TIk);
        rIdx = (rx - ox + 1) * EXTk + (rz - oz);    // buffer row = ext row + 1
        if (rOwn) {
            float4* o4 = (float4*)&out[tid * NSTEPSd];
            #pragma unroll
            for (int j = 0; j < NSTEPSd / 4; ++j) o4[j] = make_float4(0.f, 0.f, 0.f, 0.f);
        }
    }

    // V2 in 4 registers per thread: v^2*dt^2/(dx*dz), 0 in the apron.
    float rV2i[4];
    {
        const int fz = oz + ez;
        #pragma unroll
        for (int i = 0; i < 4; ++i) {
            const int fx = ox + 4 * w + i;
            float v2 = 0.f;
            if (fx >= 0 && fx < NXd && fz >= 0 && fz < NZd) {
                float v = vel[fx * NZd + fz];
                v2 = v * v * (DT2f * INVf);
            }
            rV2i[i] = v2;
        }
    }

    // Dummy LDS rows (0 and 65) zero in BOTH buffers; never rewritten.
    if (w == 0) {
        sb[0][ez] = 0.f;
        sb[0][(LROWS - 1) * EXTk + ez] = 0.f;
        sb[1][ez] = 0.f;
        sb[1][(LROWS - 1) * EXTk + ez] = 0.f;
    }

    // Source ownership (owner = lane ezs of wave exs>>2, register exs&3).
    const int sx = *src_x, sz = *src_z;
    const int exs = sx - ox, ezs = sz - oz;
    const bool srcHere = (exs >= 0 && exs < EXTk && ezs >= 0 && ezs < EXTk) &&
                         (tid == (((exs >> 2) << 6) | ezs));

    // Exact L1 cone: active at round k iff dman <= 16k+17.
    const int dxm = max(0, max(ox - sx, sx - (ox + EXTk - 1)));
    const int dzm = max(0, max(oz - sz, sz - (oz + EXTk - 1)));
    const int dman = dxm + dzm;
    const int kAct = dman <= (TBk + 1) ? 0 : (dman - (TBk + 1) + TBk - 1) / TBk;

    // Neighbor slots (lanes 0..7): d = 0 NW, 1 N, 2 NE, 3 W, 4 E, 5 SW,
    // 6 S, 7 SE (clamped; clamp->self benign: own counter == k+1 in round k).
    const int lane = tid & 63;
    int nb = myid;
    bool needL = false;           // load-side subset membership for this wave
    if (lane < 8) {
        const int d = (lane < 4) ? lane : lane + 1;       // skip center
        const int ny = min(NTILEk - 1, max(0, by + d / 3 - 1));
        const int nx = min(NTILEk - 1, max(0, bx + d % 3 - 1));
        nb = (ny * NTILEk + nx) * 32;
        // Wave w's round-k READS touch:
        //  w 0-3  : ext rows 0..15 (+ halo rows <=16) -> N band: {NW,N,NE}
        //  w 4    : own rows 16..19 (z-halo {W,E}) + huG row 15 -> +{NW,N,NE}
        //  w 5-10 : own band rows only -> {W,E}
        //  w 11   : own rows 44..47 ({W,E}) + hdG row 48 -> +{SW,S,SE}
        //  w 12-15: ext rows 48..63 (+ halo rows >=47) -> S band: {SW,S,SE}
        if (w < 4)        needL = (lane < 3);               // NW,N,NE
        else if (w == 4)  needL = (lane < 5);               // NW,N,NE,W,E
        else if (w < 11)  needL = (lane == 3 || lane == 4); // W,E
        else if (w == 11) needL = (lane >= 3);              // W,E,SW,S,SE
        else              needL = (lane >= 5);              // SW,S,SE
    }

    const int pbase = (gx0 + 4 * w) * PWk + gz0 + ez;  // padded global index
    const int fbase = 4 * w * EXTk + ez;   // buffer row 4w (ext row 4w-1)

    // Publish init + entire cone-skipped prefix in one release store
    // (barrier drains every wave's vmcnt; agent stores visible at L3).
    __syncthreads();
    if (tid == 0)
        __hip_atomic_store(&done[myid], (unsigned)(kAct + 1),
                           __ATOMIC_RELAXED, __HIP_MEMORY_SCOPE_AGENT);

    // ---- Rounds kAct..31; monotone cone => always active once started ----
    for (int k = kAct; k < NROUNDS; ++k) {
        const int t0 = TBk * k;

        // LOAD-side subset poll: wave w waits only for the neighbors its
        // own round-k reads depend on (N-half ignores a late S neighbor).
        if (needL) poll_ge(&done[nb], (unsigned)(k + 1));

        float2* __restrict__ Pin  = (k & 1) ? PB : PA;
        float2* __restrict__ Pout = (k & 1) ? PA : PB;

        // Unconditional padded agent loads (apron zeros / tolerated rim).
        float2 co[4];
        #pragma unroll
        for (int i = 0; i < 4; ++i) co[i] = ldg_f2(&Pin[pbase + i * PWk]);
        // Substep-0 x-halo direct from global: cur of ext rows 4w-1, 4w+4.
        const float huG = ldg_f1((const float*)&Pin[pbase - PWk]);
        const float hdG = ldg_f1((const float*)&Pin[pbase + 4 * PWk]);

        float rCur[4], rOld[4];
        #pragma unroll
        for (int i = 0; i < 4; ++i) { rCur[i] = co[i].x; rOld[i] = co[i].y; }

        float sv[TBk];
        if (srcHere) {
            #pragma unroll
            for (int s = 0; s < TBk; ++s) sv[s] = source[t0 + s] * DT2f;
        }

        // ---- 16 sub-steps, fully unrolled; s=0 uses global halo ----
        float rv[TBk];
        #pragma unroll
        for (int s = 0; s < TBk; ++s) {
            const float* cur = sb[s & 1];
            float* nxt = sb[(s & 1) ^ 1];
            // x-halo: s=0 from global regs; s>=1 wave-uniform ds_read2st64
            // (ext rows 4w-1, 4w+4; edge waves hit zero dummies).
            const float up0 = (s == 0) ? huG : cur[fbase];
            const float dn3 = (s == 0) ? hdG : cur[fbase + 5 * EXTk];
            float nv[4];
            #pragma unroll
            for (int i = 0; i < 4; ++i) {
                const float up = (i == 0) ? up0 : rCur[i - 1];
                const float dn = (i == 3) ? dn3 : rCur[i + 1];
                const float lf = dpp_shr1(rCur[i]);     // z-1 neighbor
                const float rt = dpp_shl1(rCur[i]);     // z+1 neighbor
                const float sum = (up + dn) + (lf + rt);
                const float t4 = __builtin_fmaf(-4.0f, rCur[i], sum);
                const float pm = __builtin_fmaf(2.0f, rCur[i], -rOld[i]);
                nv[i] = __builtin_fmaf(rV2i[i], t4, pm);
            }
            #pragma unroll
            for (int i = 0; i < 4; ++i) {
                rOld[i] = rCur[i];
                rCur[i] = nv[i];
                nxt[fbase + (1 + i) * EXTk] = nv[i];    // buffer row 4w+1+i
            }
            // Source injection (post-stencil, pre-recording).
            if (srcHere) {
                #pragma unroll
                for (int i = 0; i < 4; ++i) {
                    if (i == (exs & 3)) {
                        rCur[i] += sv[s];
                        nxt[(exs + 1) * EXTk + ezs] = rCur[i];
                    }
                }
            }
            __syncthreads();
            // Receiver sample of field@t0+s (post-injection). Next substep
            // writes the OTHER buffer -> race-free with one barrier.
            if (rOwn) rv[s] = nxt[rIdx];
        }

        // STORE-side full poll (WAR gate): Pout(k) is the buffer neighbors
        // read as Pin(k-1); all 8 must have finished round k-1 before we
        // overwrite. 16 substeps later this is nearly always satisfied.
        if (lane < 8) poll_ge(&done[nb], (unsigned)(k + 1));

        // Store interior (ext rows 16..47 = waves 4..11, ez 16..47): agent
        // stores, visible to neighbors' agent loads without any fence.
        if (w >= 4 && w < 12 && ez >= TBk && ez < EXTk - TBk) {
            #pragma unroll
            for (int i = 0; i < 4; ++i)
                stg_f2(&Pout[pbase + i * PWk], make_float2(rCur[i], rOld[i]));
        }

        // Pre-publish barrier: every wave's vmcnt (agent-store acks) drained
        // before tid 0 issues the counter store; also serializes LDS rounds.
        __syncthreads();
        if (tid == 0)
            __hip_atomic_store(&done[myid], (unsigned)(k + 2),
                               __ATOMIC_RELAXED, __HIP_MEMORY_SCOPE_AGENT);

        // Receiver flush AFTER publish (block-private, off critical path).
        if (rOwn) {
            #pragma unroll
            for (int s = 0; s < TBk; ++s)
                out[tid * NSTEPSd + t0 + s] = rv[s];
        }
    }
}

extern "C" void kernel_launch(void* const* d_in, const int* in_sizes, int n_in,
                              void* d_out, int out_size, void* d_ws, size_t ws_size,
                              hipStream_t stream) {
    const float* vel    = (const float*)d_in[0];
    const float* source = (const float*)d_in[1];
    const int*   src_x  = (const int*)d_in[2];
    const int*   src_z  = (const int*)d_in[3];
    const int*   rec_x  = (const int*)d_in[4];
    const int*   rec_z  = (const int*)d_in[5];
    float* out = (float*)d_out;

    const size_t FP = (size_t)PWk * PWk;
    // Guard rows: [guard PWk][PA FP][PB FP][guard PWk][DONE].
    float2* base = (float2*)d_ws;
    float2* PA = base + PWk;
    float2* PB = PA + FP;
    unsigned* DONE = (unsigned*)(PB + FP + PWk);   // 256 counters, 128B stride

    hipMemsetAsync(DONE, 0, (size_t)NTILEk * NTILEk * 32 * sizeof(unsigned), stream);

    void* args[] = {(void*)&vel, (void*)&source, (void*)&src_x, (void*)&src_z,
                    (void*)&rec_x, (void*)&rec_z, (void*)&PA, (void*)&PB,
                    (void*)&out, (void*)&DONE};
    hipLaunchCooperativeKernel((void*)fdtd_persist, dim3(NTILEk, NTILEk),
                               dim3(1024), args, 0, stream);
}